// Round 1
// baseline (2347.840 us; speedup 1.0000x reference)
//
#include <hip/hip_runtime.h>

// Shapes (fixed by setup_inputs): B=4, T=2048, C=768, H=8, hs=96
constexpr int Bn = 4;
constexpr int Tn = 2048;
constexpr int Cn = 768;
constexpr int Hn = 8;
constexpr int HSn = 96;           // head size
constexpr int MR = Bn * Tn;       // 8192 rows
constexpr int NQKV = 3 * Cn;      // 2304

// ---------------------------------------------------------------------------
// GEMM with bias: C[M,N] = A[M,K] @ W[K,N] + bias[N]
// 64x64 tile, BK=16, 256 threads, 4x4 register micro-tile per thread.
// ---------------------------------------------------------------------------
template <int BM, int BN, int BK>
__global__ __launch_bounds__(256) void gemm_bias(
    const float* __restrict__ A, const float* __restrict__ W,
    const float* __restrict__ bias, float* __restrict__ Cout,
    int M, int N, int K) {
  // +4 pad keeps 16B alignment for ds_read_b128 and spreads banks.
  __shared__ float As[BK][BM + 4];
  __shared__ float Bs[BK][BN + 4];

  const int tid = threadIdx.x;
  const int tc = tid & 15;   // output n-group
  const int tr = tid >> 4;   // output m-group
  const int bm = blockIdx.y * BM;
  const int bn = blockIdx.x * BN;

  float acc[4][4] = {};

  for (int k0 = 0; k0 < K; k0 += BK) {
    #pragma unroll
    for (int i = tid; i < BM * BK; i += 256) {
      const int m = i / BK, k = i % BK;          // consecutive tid -> consecutive k (coalesced)
      As[k][m] = A[(size_t)(bm + m) * K + k0 + k];
    }
    #pragma unroll
    for (int i = tid; i < BK * BN; i += 256) {
      const int k = i / BN, n = i % BN;          // consecutive tid -> consecutive n (coalesced)
      Bs[k][n] = W[(size_t)(k0 + k) * N + bn + n];
    }
    __syncthreads();

    #pragma unroll
    for (int k = 0; k < BK; ++k) {
      float av[4], bv[4];
      #pragma unroll
      for (int i = 0; i < 4; ++i) av[i] = As[k][tr * 4 + i];
      #pragma unroll
      for (int j = 0; j < 4; ++j) bv[j] = Bs[k][tc * 4 + j];
      #pragma unroll
      for (int i = 0; i < 4; ++i)
        #pragma unroll
        for (int j = 0; j < 4; ++j)
          acc[i][j] = fmaf(av[i], bv[j], acc[i][j]);
    }
    __syncthreads();
  }

  #pragma unroll
  for (int i = 0; i < 4; ++i) {
    const int m = bm + tr * 4 + i;
    #pragma unroll
    for (int j = 0; j < 4; ++j) {
      const int n = bn + tc * 4 + j;
      Cout[(size_t)m * N + n] = acc[i][j] + bias[n];
    }
  }
}

// ---------------------------------------------------------------------------
// Causal flash attention, fp32, online softmax.
// Block = 256 threads = 64 query rows x 4 d-parts (24 dims each).
// Grid = (T/64, H, B). Reads q/k/v straight out of qkv [B,T,3C];
// writes y in [B,T,C] (already output-reordered).
// Softmax matches reference: exp(s - rowmax) / (sum + 1e-6).
// ---------------------------------------------------------------------------
__global__ __launch_bounds__(256) void attn_kernel(
    const float* __restrict__ qkv, float* __restrict__ y) {
  const int qt = blockIdx.x;
  const int h  = blockIdx.y;
  const int b  = blockIdx.z;
  const int tid  = threadIdx.x;
  const int row  = tid >> 2;   // 0..63 query row within tile
  const int part = tid & 3;    // 0..3 chunk of 24 dims
  const int qi   = qt * 64 + row;

  __shared__ float Kt[64][HSn];   // 24 KB
  __shared__ float Vt[64][HSn];   // 24 KB
  __shared__ float S[64][64];     // 16 KB, indexed [key][row] => conflict-free

  const float scale = 0.102062072615966f;  // 1/sqrt(96)

  float q_reg[24], acc[24];
  const size_t qrow = ((size_t)(b * Tn + qi)) * NQKV + h * HSn;
  #pragma unroll
  for (int d = 0; d < 24; ++d) {
    q_reg[d] = qkv[qrow + part * 24 + d];
    acc[d] = 0.f;
  }
  float m = -1e30f, l = 0.f;

  const int ktiles = qt + 1;
  for (int kt = 0; kt < ktiles; ++kt) {
    const int k0 = kt * 64;
    __syncthreads();  // protect Kt/Vt from previous iteration's readers
    for (int i = tid; i < 64 * HSn; i += 256) {
      const int j = i / HSn, dd = i % HSn;
      const size_t rb = ((size_t)(b * Tn + k0 + j)) * NQKV + h * HSn + dd;
      Kt[j][dd] = qkv[rb + Cn];        // K block
      Vt[j][dd] = qkv[rb + 2 * Cn];    // V block
    }
    __syncthreads();

    // --- scores: each thread computes a 24-dim partial dot for all 64 keys,
    //     reduced across the 4 part-threads (same wave) via shfl_xor.
    float tmax = -1e30f;
    #pragma unroll 8
    for (int j = 0; j < 64; ++j) {
      float s = 0.f;
      #pragma unroll
      for (int d = 0; d < 24; ++d)
        s = fmaf(q_reg[d], Kt[j][part * 24 + d], s);
      s += __shfl_xor(s, 1);
      s += __shfl_xor(s, 2);
      s *= scale;
      if (k0 + j > qi) s = -1e30f;     // causal mask
      if (part == 0) S[j][row] = s;    // same-wave producer/consumer, no barrier needed
      tmax = fmaxf(tmax, s);
    }

    // --- online softmax update (identical on all 4 parts of a row)
    const float mnew = fmaxf(m, tmax);
    const float corr = __expf(m - mnew);
    l *= corr;
    #pragma unroll
    for (int d = 0; d < 24; ++d) acc[d] *= corr;

    float lsum = 0.f;
    #pragma unroll 8
    for (int j = 0; j < 64; ++j) {
      const float p = __expf(S[j][row] - mnew);
      lsum += p;
      #pragma unroll
      for (int d = 0; d < 24; ++d)
        acc[d] = fmaf(p, Vt[j][part * 24 + d], acc[d]);
    }
    l += lsum;
    m = mnew;
  }

  const float inv = 1.f / (l + 1e-6f);  // matches reference eps
  const size_t ob = ((size_t)(b * Tn + qi)) * Cn + h * HSn + part * 24;
  #pragma unroll
  for (int d = 0; d < 24; ++d)
    y[ob + d] = acc[d] * inv;
}

// ---------------------------------------------------------------------------
extern "C" void kernel_launch(void* const* d_in, const int* in_sizes, int n_in,
                              void* d_out, int out_size, void* d_ws, size_t ws_size,
                              hipStream_t stream) {
  const float* x      = (const float*)d_in[0];
  const float* w_attn = (const float*)d_in[1];
  const float* b_attn = (const float*)d_in[2];
  const float* w_proj = (const float*)d_in[3];
  const float* b_proj = (const float*)d_in[4];
  float* out = (float*)d_out;

  // workspace layout: qkv [8192][2304] fp32, then y [8192][768] fp32
  const size_t qkv_elems = (size_t)MR * NQKV;      // 18,874,368
  const size_t y_elems   = (size_t)MR * Cn;        //  6,291,456
  if (ws_size < (qkv_elems + y_elems) * sizeof(float)) return;  // fail loudly via validation
  float* qkv = (float*)d_ws;
  float* yb  = qkv + qkv_elems;

  // 1) qkv = x @ w_attn + b_attn
  gemm_bias<64, 64, 16><<<dim3(NQKV / 64, MR / 64), 256, 0, stream>>>(
      x, w_attn, b_attn, qkv, MR, NQKV, Cn);

  // 2) causal attention -> y (already [B,T,C])
  attn_kernel<<<dim3(Tn / 64, Hn, Bn), 256, 0, stream>>>(qkv, yb);

  // 3) out = y @ w_proj + b_proj
  gemm_bias<64, 64, 16><<<dim3(Cn / 64, MR / 64), 256, 0, stream>>>(
      yb, w_proj, b_proj, out, MR, Cn, Cn);
}

// Round 2
// 694.282 us; speedup vs baseline: 3.3817x; 3.3817x over previous
//
#include <hip/hip_runtime.h>

// Shapes (fixed): B=4, T=2048, C=768, H=8, hs=96
constexpr int Bn = 4;
constexpr int Tn = 2048;
constexpr int Cn = 768;
constexpr int Hn = 8;
constexpr int HSn = 96;
constexpr int MR = Bn * Tn;       // 8192
constexpr int NQKV = 3 * Cn;      // 2304

typedef __attribute__((ext_vector_type(8))) short bf16x8;
typedef __attribute__((ext_vector_type(4))) float f32x4;

__device__ inline short f2bf(float f) {
  union { float f; unsigned u; } cv; cv.f = f;
  unsigned u = cv.u;
  u += 0x7fffu + ((u >> 16) & 1u);   // RNE; inputs are finite
  return (short)(u >> 16);
}

// ---------------------------------------------------------------------------
// fp32 GEMM with bias: C[M,N] = A[M,K] @ W[K,N] + bias[N].
// BF16OUT: write bf16, scaling the first scale_cols columns by `scale`
// (used to fold the attention 1/sqrt(hs) into the q block of qkv).
// ---------------------------------------------------------------------------
template <int BM, int BN, int BK, bool BF16OUT>
__global__ __launch_bounds__(256) void gemm_bias(
    const float* __restrict__ A, const float* __restrict__ W,
    const float* __restrict__ bias, float* __restrict__ Cf,
    short* __restrict__ Cb, int M, int N, int K, int scale_cols, float scale) {
  __shared__ float As[BK][BM + 4];
  __shared__ float Bs[BK][BN + 4];

  const int tid = threadIdx.x;
  const int tc = tid & 15;
  const int tr = tid >> 4;
  const int bm = blockIdx.y * BM;
  const int bn = blockIdx.x * BN;

  float acc[4][4] = {};

  for (int k0 = 0; k0 < K; k0 += BK) {
    #pragma unroll
    for (int i = tid; i < BM * BK; i += 256) {
      const int m = i / BK, k = i % BK;
      As[k][m] = A[(size_t)(bm + m) * K + k0 + k];
    }
    #pragma unroll
    for (int i = tid; i < BK * BN; i += 256) {
      const int k = i / BN, n = i % BN;
      Bs[k][n] = W[(size_t)(k0 + k) * N + bn + n];
    }
    __syncthreads();

    #pragma unroll
    for (int k = 0; k < BK; ++k) {
      float av[4], bv[4];
      #pragma unroll
      for (int i = 0; i < 4; ++i) av[i] = As[k][tr * 4 + i];
      #pragma unroll
      for (int j = 0; j < 4; ++j) bv[j] = Bs[k][tc * 4 + j];
      #pragma unroll
      for (int i = 0; i < 4; ++i)
        #pragma unroll
        for (int j = 0; j < 4; ++j)
          acc[i][j] = fmaf(av[i], bv[j], acc[i][j]);
    }
    __syncthreads();
  }

  #pragma unroll
  for (int i = 0; i < 4; ++i) {
    const int m = bm + tr * 4 + i;
    #pragma unroll
    for (int j = 0; j < 4; ++j) {
      const int n = bn + tc * 4 + j;
      float v = acc[i][j] + bias[n];
      if (BF16OUT) {
        if (n < scale_cols) v *= scale;
        Cb[(size_t)m * N + n] = f2bf(v);
      } else {
        Cf[(size_t)m * N + n] = v;
      }
    }
  }
}

// ---------------------------------------------------------------------------
// Causal flash attention with bf16 MFMA (16x16x32), fp32 accumulate.
// Block = 256 threads = 4 waves; each wave owns 16 q-rows.
// Block bx handles q-tiles {bx, 31-bx} -> every block does exactly 33 KV
// tiles (causal load balance). Grid (16, H, B) = 512 blocks.
//
// Fragment layouts (gfx950, measured in guide):
//   A: row = lane&15,        k  = (lane>>4)*8 + j   (8 consecutive bf16)
//   B: col = lane&15,        k  = (lane>>4)*8 + j
//   D: col = lane&15,        row= (lane>>4)*4 + reg
// ---------------------------------------------------------------------------
__global__ __launch_bounds__(256) void attn_mfma(
    const short* __restrict__ qkv, float* __restrict__ y) {
  __shared__ short Ks[64][104];     // [key][dim], row 208 B (13,312 B)
  __shared__ short Vt[96][72];      // [dim][key] transposed, row 144 B (13,824 B)
  __shared__ short Pl[4][16][72];   // per-wave P[qrow][key] (9,216 B)

  const int bx = blockIdx.x;
  const int h  = blockIdx.y;
  const int b  = blockIdx.z;
  const int tid  = threadIdx.x;
  const int wave = tid >> 6;
  const int lane = tid & 63;
  const int g = lane >> 4;
  const int c = lane & 15;

  for (int phase = 0; phase < 2; ++phase) {
    const int qt = phase ? (31 - bx) : bx;
    const int q0 = qt * 64 + wave * 16;

    // Q fragments, held in registers for the whole q-tile (scale pre-folded).
    bf16x8 qf[3];
    {
      const size_t qb = ((size_t)(b * Tn + q0 + c)) * NQKV + h * HSn;
      #pragma unroll
      for (int kk = 0; kk < 3; ++kk)
        qf[kk] = *(const bf16x8*)(qkv + qb + kk * 32 + g * 8);
    }

    f32x4 yacc[6] = {};
    float mrow[4] = {-1e30f, -1e30f, -1e30f, -1e30f};
    float lrow[4] = {};

    for (int kt = 0; kt <= qt; ++kt) {
      const int k0 = kt * 64;
      __syncthreads();   // previous tile's readers done before restaging
      // --- stage K: [key][dim], chunk-major (coalesced global rows)
      for (int i = tid; i < 768; i += 256) {
        const int r = i / 12, ch = i % 12;
        *(bf16x8*)&Ks[r][ch * 8] = *(const bf16x8*)(
            qkv + ((size_t)(b * Tn + k0 + r)) * NQKV + Cn + h * HSn + ch * 8);
      }
      // --- stage V transposed: key-major lanes => conflict-free b16 LDS writes
      for (int i = tid; i < 768; i += 256) {
        const int r = i & 63, ch = i >> 6;
        bf16x8 v = *(const bf16x8*)(
            qkv + ((size_t)(b * Tn + k0 + r)) * NQKV + 2 * Cn + h * HSn + ch * 8);
        #pragma unroll
        for (int j = 0; j < 8; ++j) Vt[ch * 8 + j][r] = v[j];
      }
      __syncthreads();

      // --- S = Q K^T (scale folded into Q)
      f32x4 s[4] = {};
      #pragma unroll
      for (int kk = 0; kk < 3; ++kk) {
        #pragma unroll
        for (int t = 0; t < 4; ++t) {
          bf16x8 kf = *(const bf16x8*)&Ks[16 * t + c][32 * kk + g * 8];
          s[t] = __builtin_amdgcn_mfma_f32_16x16x32_bf16(qf[kk], kf, s[t], 0, 0, 0);
        }
      }
      if (kt == qt) {   // causal mask only touches the diagonal tile
        #pragma unroll
        for (int t = 0; t < 4; ++t)
          #pragma unroll
          for (int r = 0; r < 4; ++r)
            if (k0 + 16 * t + c > q0 + 4 * g + r) s[t][r] = -1e30f;
      }

      // --- online softmax (rows 4g+r live in the 16 lanes of group g)
      #pragma unroll
      for (int r = 0; r < 4; ++r) {
        float mx = fmaxf(fmaxf(s[0][r], s[1][r]), fmaxf(s[2][r], s[3][r]));
        mx = fmaxf(mx, __shfl_xor(mx, 1));
        mx = fmaxf(mx, __shfl_xor(mx, 2));
        mx = fmaxf(mx, __shfl_xor(mx, 4));
        mx = fmaxf(mx, __shfl_xor(mx, 8));
        const float mnew = fmaxf(mrow[r], mx);
        const float corr = __expf(mrow[r] - mnew);
        mrow[r] = mnew;
        lrow[r] *= corr;
        #pragma unroll
        for (int dt = 0; dt < 6; ++dt) yacc[dt][r] *= corr;
        float ls = 0.f;
        #pragma unroll
        for (int t = 0; t < 4; ++t) {
          const float p = __expf(s[t][r] - mnew);
          ls += p;
          Pl[wave][4 * g + r][16 * t + c] = f2bf(p);
        }
        lrow[r] += ls;   // per-lane partial; cross-lane reduce deferred to end
      }

      // --- Y += P V  (P via same-wave LDS round-trip, no barrier needed)
      #pragma unroll
      for (int ks = 0; ks < 2; ++ks) {
        bf16x8 pf = *(const bf16x8*)&Pl[wave][c][ks * 32 + g * 8];
        #pragma unroll
        for (int dt = 0; dt < 6; ++dt) {
          bf16x8 vf = *(const bf16x8*)&Vt[16 * dt + c][ks * 32 + g * 8];
          yacc[dt] = __builtin_amdgcn_mfma_f32_16x16x32_bf16(pf, vf, yacc[dt], 0, 0, 0);
        }
      }
    }

    // --- epilogue: finish row sums, normalize, store fp32 y in [B,T,C]
    #pragma unroll
    for (int r = 0; r < 4; ++r) {
      float v = lrow[r];
      v += __shfl_xor(v, 1);
      v += __shfl_xor(v, 2);
      v += __shfl_xor(v, 4);
      v += __shfl_xor(v, 8);
      lrow[r] = 1.f / (v + 1e-6f);
    }
    #pragma unroll
    for (int dt = 0; dt < 6; ++dt)
      #pragma unroll
      for (int r = 0; r < 4; ++r)
        y[((size_t)(b * Tn + q0 + 4 * g + r)) * Cn + h * HSn + 16 * dt + c] =
            yacc[dt][r] * lrow[r];
  }
}

// ---------------------------------------------------------------------------
extern "C" void kernel_launch(void* const* d_in, const int* in_sizes, int n_in,
                              void* d_out, int out_size, void* d_ws, size_t ws_size,
                              hipStream_t stream) {
  const float* x      = (const float*)d_in[0];
  const float* w_attn = (const float*)d_in[1];
  const float* b_attn = (const float*)d_in[2];
  const float* w_proj = (const float*)d_in[3];
  const float* b_proj = (const float*)d_in[4];
  float* out = (float*)d_out;

  // ws: qkv bf16 [8192][2304] (37.75 MB), then y fp32 [8192][768] (25.2 MB)
  const size_t qkv_elems = (size_t)MR * NQKV;
  const size_t qkv_bytes = qkv_elems * sizeof(short);
  const size_t y_bytes   = (size_t)MR * Cn * sizeof(float);
  if (ws_size < qkv_bytes + y_bytes) return;
  short* qkv_bf = (short*)d_ws;
  float* yb     = (float*)((char*)d_ws + qkv_bytes);

  const float scale = 0.102062072615966f;  // 1/sqrt(96)

  // 1) qkv = x @ w_attn + b_attn  (bf16 out, q columns pre-scaled)
  gemm_bias<64, 64, 16, true><<<dim3(NQKV / 64, MR / 64), 256, 0, stream>>>(
      x, w_attn, b_attn, nullptr, qkv_bf, MR, NQKV, Cn, Cn, scale);

  // 2) causal MFMA attention -> y (fp32, already [B,T,C])
  attn_mfma<<<dim3(16, Hn, Bn), 256, 0, stream>>>(qkv_bf, yb);

  // 3) out = y @ w_proj + b_proj (fp32)
  gemm_bias<64, 64, 16, false><<<dim3(Cn / 64, MR / 64), 256, 0, stream>>>(
      yb, w_proj, b_proj, out, nullptr, MR, Cn, Cn, 0, 1.f);
}

// Round 3
// 224.097 us; speedup vs baseline: 10.4769x; 3.0981x over previous
//
#include <hip/hip_runtime.h>

// Shapes (fixed): B=4, T=2048, C=768, H=8, hs=96
constexpr int Bn = 4;
constexpr int Tn = 2048;
constexpr int Cn = 768;
constexpr int Hn = 8;
constexpr int HSn = 96;
constexpr int MR = Bn * Tn;       // 8192
constexpr int NQKV = 3 * Cn;      // 2304

typedef __attribute__((ext_vector_type(8))) short bf16x8;
typedef __attribute__((ext_vector_type(4))) float f32x4;
typedef __attribute__((ext_vector_type(4))) short short4v;

__device__ inline short f2bf(float f) {
  union { float f; unsigned u; } cv; cv.f = f;
  unsigned u = cv.u;
  u += 0x7fffu + ((u >> 16) & 1u);   // RNE; inputs are finite
  return (short)(u >> 16);
}

__device__ inline void gload_lds16(const short* g, short* l) {
  __builtin_amdgcn_global_load_lds(
      (const __attribute__((address_space(1))) unsigned*)g,
      (__attribute__((address_space(3))) unsigned*)l, 16, 0, 0);
}

// ---------------------------------------------------------------------------
// fp32 -> bf16 elementwise (8 elems/thread, exact grid)
// ---------------------------------------------------------------------------
__global__ __launch_bounds__(256) void cvt_bf16(const float* __restrict__ in,
                                                short* __restrict__ out) {
  const size_t i = ((size_t)blockIdx.x * 256 + threadIdx.x) * 8;
  float4 a = *(const float4*)(in + i);
  float4 b = *(const float4*)(in + i + 4);
  bf16x8 o;
  o[0] = f2bf(a.x); o[1] = f2bf(a.y); o[2] = f2bf(a.z); o[3] = f2bf(a.w);
  o[4] = f2bf(b.x); o[5] = f2bf(b.y); o[6] = f2bf(b.z); o[7] = f2bf(b.w);
  *(bf16x8*)(out + i) = o;
}

// ---------------------------------------------------------------------------
// W [K][N] fp32 -> Wt [N][K] bf16 (32x32 LDS tile transpose)
// ---------------------------------------------------------------------------
__global__ __launch_bounds__(256) void transpose_bf16(
    const float* __restrict__ W, short* __restrict__ Wt, int K, int N) {
  __shared__ float t[32][33];
  const int n0 = blockIdx.x * 32, k0 = blockIdx.y * 32;
  const int tx = threadIdx.x & 31, ty = threadIdx.x >> 5;  // 8 rows/pass
  #pragma unroll
  for (int i = 0; i < 32; i += 8)
    t[ty + i][tx] = W[(size_t)(k0 + ty + i) * N + n0 + tx];
  __syncthreads();
  #pragma unroll
  for (int i = 0; i < 32; i += 8)
    Wt[(size_t)(n0 + ty + i) * K + k0 + tx] = f2bf(t[tx][ty + i]);
}

// ---------------------------------------------------------------------------
// bf16 MFMA GEMM (m97 structure): C[M,N] = A[M,K] @ Bt[N,K]^T + bias[N]
// 128x128 tile, BK=32, 4 waves (2x2), 4x4 16x16x32 fragments per wave,
// global_load_lds width=16 staging into linear LDS, 2-barrier K loop.
// ---------------------------------------------------------------------------
template <bool BF16OUT>
__global__ __launch_bounds__(256) void gemm_mfma(
    const short* __restrict__ A, const short* __restrict__ Bt,
    const float* __restrict__ bias, float* __restrict__ Cf,
    short* __restrict__ Cb, int M, int N, int K, int scale_cols, float scale) {
  __shared__ short As[128 * 32];   // 8 KB, linear [row][k] rows of 64 B
  __shared__ short Bs[128 * 32];   // 8 KB

  const int tid  = threadIdx.x;
  const int wave = tid >> 6, lane = tid & 63;
  const int bm = blockIdx.y * 128, bn = blockIdx.x * 128;
  const int wr = wave >> 1, wc = wave & 1;
  const int g = lane >> 4, c = lane & 15;

  f32x4 acc[4][4] = {};

  for (int k0 = 0; k0 < K; k0 += 32) {
    __syncthreads();   // previous iteration's readers done
    #pragma unroll
    for (int cc = 0; cc < 2; ++cc) {
      const int chunkbase = (wave * 2 + cc) * 64;       // 16B-chunk index base
      const int chunk = chunkbase + lane;
      const int row = chunk >> 2, col16 = chunk & 3;    // row 0..127, 4 chunks/row
      gload_lds16(A + (size_t)(bm + row) * K + k0 + col16 * 8,
                  &As[chunkbase * 8]);
      gload_lds16(Bt + (size_t)(bn + row) * K + k0 + col16 * 8,
                  &Bs[chunkbase * 8]);
    }
    __syncthreads();   // drain vmcnt + make LDS visible

    bf16x8 af[4], bf[4];
    #pragma unroll
    for (int m = 0; m < 4; ++m)
      af[m] = *(const bf16x8*)&As[(wr * 64 + m * 16 + c) * 32 + g * 8];
    #pragma unroll
    for (int n = 0; n < 4; ++n)
      bf[n] = *(const bf16x8*)&Bs[(wc * 64 + n * 16 + c) * 32 + g * 8];
    #pragma unroll
    for (int m = 0; m < 4; ++m)
      #pragma unroll
      for (int n = 0; n < 4; ++n)
        acc[m][n] = __builtin_amdgcn_mfma_f32_16x16x32_bf16(af[m], bf[n], acc[m][n], 0, 0, 0);
  }

  #pragma unroll
  for (int n = 0; n < 4; ++n) {
    const int col = bn + wc * 64 + n * 16 + c;
    const float bs = bias[col];
    const float sc = (BF16OUT && col < scale_cols) ? scale : 1.f;
    #pragma unroll
    for (int m = 0; m < 4; ++m) {
      #pragma unroll
      for (int r = 0; r < 4; ++r) {
        const int row = bm + wr * 64 + m * 16 + g * 4 + r;
        const float v = acc[m][n][r] + bs;
        if (BF16OUT) Cb[(size_t)row * N + col] = f2bf(v * sc);
        else         Cf[(size_t)row * N + col] = v;
      }
    }
  }
}

// ---------------------------------------------------------------------------
// Causal flash attention with bf16 MFMA (16x16x32), fp32 accumulate.
// Block = 4 waves; each wave owns 16 q-rows. Block bx handles q-tiles
// {bx, 31-bx} (causal load balance). Writes y as bf16 [B,T,C].
// ---------------------------------------------------------------------------
__global__ __launch_bounds__(256) void attn_mfma(
    const short* __restrict__ qkv, short* __restrict__ y) {
  __shared__ short Ks[64][104];
  __shared__ short Vt[96][72];
  __shared__ short Pl[4][16][72];

  const int bx = blockIdx.x;
  const int h  = blockIdx.y;
  const int b  = blockIdx.z;
  const int tid  = threadIdx.x;
  const int wave = tid >> 6;
  const int lane = tid & 63;
  const int g = lane >> 4;
  const int c = lane & 15;

  for (int phase = 0; phase < 2; ++phase) {
    const int qt = phase ? (31 - bx) : bx;
    const int q0 = qt * 64 + wave * 16;

    bf16x8 qf[3];
    {
      const size_t qb = ((size_t)(b * Tn + q0 + c)) * NQKV + h * HSn;
      #pragma unroll
      for (int kk = 0; kk < 3; ++kk)
        qf[kk] = *(const bf16x8*)(qkv + qb + kk * 32 + g * 8);
    }

    f32x4 yacc[6] = {};
    float mrow[4] = {-1e30f, -1e30f, -1e30f, -1e30f};
    float lrow[4] = {};

    for (int kt = 0; kt <= qt; ++kt) {
      const int k0 = kt * 64;
      __syncthreads();
      for (int i = tid; i < 768; i += 256) {
        const int r = i / 12, ch = i % 12;
        *(bf16x8*)&Ks[r][ch * 8] = *(const bf16x8*)(
            qkv + ((size_t)(b * Tn + k0 + r)) * NQKV + Cn + h * HSn + ch * 8);
      }
      for (int i = tid; i < 768; i += 256) {
        const int r = i & 63, ch = i >> 6;
        bf16x8 v = *(const bf16x8*)(
            qkv + ((size_t)(b * Tn + k0 + r)) * NQKV + 2 * Cn + h * HSn + ch * 8);
        #pragma unroll
        for (int j = 0; j < 8; ++j) Vt[ch * 8 + j][r] = v[j];
      }
      __syncthreads();

      f32x4 s[4] = {};
      #pragma unroll
      for (int kk = 0; kk < 3; ++kk) {
        #pragma unroll
        for (int t = 0; t < 4; ++t) {
          bf16x8 kf = *(const bf16x8*)&Ks[16 * t + c][32 * kk + g * 8];
          s[t] = __builtin_amdgcn_mfma_f32_16x16x32_bf16(qf[kk], kf, s[t], 0, 0, 0);
        }
      }
      if (kt == qt) {
        #pragma unroll
        for (int t = 0; t < 4; ++t)
          #pragma unroll
          for (int r = 0; r < 4; ++r)
            if (k0 + 16 * t + c > q0 + 4 * g + r) s[t][r] = -1e30f;
      }

      #pragma unroll
      for (int r = 0; r < 4; ++r) {
        float mx = fmaxf(fmaxf(s[0][r], s[1][r]), fmaxf(s[2][r], s[3][r]));
        mx = fmaxf(mx, __shfl_xor(mx, 1));
        mx = fmaxf(mx, __shfl_xor(mx, 2));
        mx = fmaxf(mx, __shfl_xor(mx, 4));
        mx = fmaxf(mx, __shfl_xor(mx, 8));
        const float mnew = fmaxf(mrow[r], mx);
        const float corr = __expf(mrow[r] - mnew);
        mrow[r] = mnew;
        lrow[r] *= corr;
        #pragma unroll
        for (int dt = 0; dt < 6; ++dt) yacc[dt][r] *= corr;
        float ls = 0.f;
        #pragma unroll
        for (int t = 0; t < 4; ++t) {
          const float p = __expf(s[t][r] - mnew);
          ls += p;
          Pl[wave][4 * g + r][16 * t + c] = f2bf(p);
        }
        lrow[r] += ls;
      }

      #pragma unroll
      for (int ks = 0; ks < 2; ++ks) {
        bf16x8 pf = *(const bf16x8*)&Pl[wave][c][ks * 32 + g * 8];
        #pragma unroll
        for (int dt = 0; dt < 6; ++dt) {
          bf16x8 vf = *(const bf16x8*)&Vt[16 * dt + c][ks * 32 + g * 8];
          yacc[dt] = __builtin_amdgcn_mfma_f32_16x16x32_bf16(pf, vf, yacc[dt], 0, 0, 0);
        }
      }
    }

    #pragma unroll
    for (int r = 0; r < 4; ++r) {
      float v = lrow[r];
      v += __shfl_xor(v, 1);
      v += __shfl_xor(v, 2);
      v += __shfl_xor(v, 4);
      v += __shfl_xor(v, 8);
      lrow[r] = 1.f / (v + 1e-6f);
    }
    #pragma unroll
    for (int dt = 0; dt < 6; ++dt)
      #pragma unroll
      for (int r = 0; r < 4; ++r)
        y[((size_t)(b * Tn + q0 + 4 * g + r)) * Cn + h * HSn + 16 * dt + c] =
            f2bf(yacc[dt][r] * lrow[r]);
  }
}

// ---------------------------------------------------------------------------
extern "C" void kernel_launch(void* const* d_in, const int* in_sizes, int n_in,
                              void* d_out, int out_size, void* d_ws, size_t ws_size,
                              hipStream_t stream) {
  const float* x      = (const float*)d_in[0];
  const float* w_attn = (const float*)d_in[1];
  const float* b_attn = (const float*)d_in[2];
  const float* w_proj = (const float*)d_in[3];
  const float* b_proj = (const float*)d_in[4];
  float* out = (float*)d_out;

  // workspace layout (bf16 shorts unless noted):
  //   qkv [8192][2304]  37,748,736 B
  //   xb  [8192][768]   12,582,912 B
  //   yb  [8192][768]   12,582,912 B
  //   wat [2304][768]    3,538,944 B   (w_attn transposed)
  //   wpt [768][768]     1,179,648 B   (w_proj transposed)
  size_t off = 0;
  short* qkv = (short*)((char*)d_ws + off); off += (size_t)MR * NQKV * 2;
  short* xb  = (short*)((char*)d_ws + off); off += (size_t)MR * Cn * 2;
  short* yb  = (short*)((char*)d_ws + off); off += (size_t)MR * Cn * 2;
  short* wat = (short*)((char*)d_ws + off); off += (size_t)Cn * NQKV * 2;
  short* wpt = (short*)((char*)d_ws + off); off += (size_t)Cn * Cn * 2;
  if (ws_size < off) return;

  const float scale = 0.102062072615966f;  // 1/sqrt(96)

  // 0) precision prep: x -> bf16; weights -> transposed bf16
  cvt_bf16<<<(MR * Cn) / (256 * 8), 256, 0, stream>>>(x, xb);
  transpose_bf16<<<dim3(NQKV / 32, Cn / 32), 256, 0, stream>>>(w_attn, wat, Cn, NQKV);
  transpose_bf16<<<dim3(Cn / 32, Cn / 32), 256, 0, stream>>>(w_proj, wpt, Cn, Cn);

  // 1) qkv = x @ w_attn + b_attn   (bf16 out, q columns pre-scaled)
  gemm_mfma<true><<<dim3(NQKV / 128, MR / 128), 256, 0, stream>>>(
      xb, wat, b_attn, nullptr, qkv, MR, NQKV, Cn, Cn, scale);

  // 2) causal MFMA attention -> y bf16 [B,T,C]
  attn_mfma<<<dim3(16, Hn, Bn), 256, 0, stream>>>(qkv, yb);

  // 3) out = y @ w_proj + b_proj   (fp32 out)
  gemm_mfma<false><<<dim3(Cn / 128, MR / 128), 256, 0, stream>>>(
      yb, wpt, b_proj, out, nullptr, MR, Cn, Cn, 0, 1.f);
}

// Round 4
// 162.432 us; speedup vs baseline: 14.4543x; 1.3796x over previous
//
#include <hip/hip_runtime.h>

// Shapes (fixed): B=4, T=2048, C=768, H=8, hs=96
constexpr int Bn = 4;
constexpr int Tn = 2048;
constexpr int Cn = 768;
constexpr int Hn = 8;
constexpr int HSn = 96;
constexpr int MR = Bn * Tn;       // 8192
constexpr int NQKV = 3 * Cn;      // 2304

typedef __attribute__((ext_vector_type(8))) short bf16x8;
typedef __attribute__((ext_vector_type(4))) float f32x4;

__device__ inline short f2bf(float f) {
  union { float f; unsigned u; } cv; cv.f = f;
  unsigned u = cv.u;
  u += 0x7fffu + ((u >> 16) & 1u);   // RNE; inputs are finite
  return (short)(u >> 16);
}

__device__ inline void gload_lds16(const short* g, short* l) {
  __builtin_amdgcn_global_load_lds(
      (const __attribute__((address_space(1))) unsigned*)g,
      (__attribute__((address_space(3))) unsigned*)l, 16, 0, 0);
}

// ---------------------------------------------------------------------------
// fp32 -> bf16 elementwise (8 elems/thread, exact grid)
// ---------------------------------------------------------------------------
__global__ __launch_bounds__(256) void cvt_bf16(const float* __restrict__ in,
                                                short* __restrict__ out) {
  const size_t i = ((size_t)blockIdx.x * 256 + threadIdx.x) * 8;
  float4 a = *(const float4*)(in + i);
  float4 b = *(const float4*)(in + i + 4);
  bf16x8 o;
  o[0] = f2bf(a.x); o[1] = f2bf(a.y); o[2] = f2bf(a.z); o[3] = f2bf(a.w);
  o[4] = f2bf(b.x); o[5] = f2bf(b.y); o[6] = f2bf(b.z); o[7] = f2bf(b.w);
  *(bf16x8*)(out + i) = o;
}

// ---------------------------------------------------------------------------
// W [K][N] fp32 -> Wt [N][K] bf16 (32x32 LDS tile transpose)
// ---------------------------------------------------------------------------
__global__ __launch_bounds__(256) void transpose_bf16(
    const float* __restrict__ W, short* __restrict__ Wt, int K, int N) {
  __shared__ float t[32][33];
  const int n0 = blockIdx.x * 32, k0 = blockIdx.y * 32;
  const int tx = threadIdx.x & 31, ty = threadIdx.x >> 5;
  #pragma unroll
  for (int i = 0; i < 32; i += 8)
    t[ty + i][tx] = W[(size_t)(k0 + ty + i) * N + n0 + tx];
  __syncthreads();
  #pragma unroll
  for (int i = 0; i < 32; i += 8)
    Wt[(size_t)(n0 + ty + i) * K + k0 + tx] = f2bf(t[tx][ty + i]);
}

// ---------------------------------------------------------------------------
// bf16 MFMA GEMM (m97 structure): C[M,N] = A[M,K] @ Bt[N,K]^T + bias[N]
// 1D grid with bijective XCD-chunked remap (gridDim.x % 8 == 0).
// ---------------------------------------------------------------------------
template <bool BF16OUT>
__global__ __launch_bounds__(256) void gemm_mfma(
    const short* __restrict__ A, const short* __restrict__ Bt,
    const float* __restrict__ bias, float* __restrict__ Cf,
    short* __restrict__ Cb, int M, int N, int K, int nxTiles,
    int scale_cols, float scale) {
  __shared__ short As[128 * 32];
  __shared__ short Bs[128 * 32];

  const int cpx = gridDim.x >> 3;
  const int lin = blockIdx.x;
  const int remap = (lin & 7) * cpx + (lin >> 3);   // XCD-chunked, bijective
  const int bxt = remap % nxTiles, byt = remap / nxTiles;

  const int tid  = threadIdx.x;
  const int wave = tid >> 6, lane = tid & 63;
  const int bm = byt * 128, bn = bxt * 128;
  const int wr = wave >> 1, wc = wave & 1;
  const int g = lane >> 4, c = lane & 15;

  f32x4 acc[4][4] = {};

  for (int k0 = 0; k0 < K; k0 += 32) {
    __syncthreads();
    #pragma unroll
    for (int cc = 0; cc < 2; ++cc) {
      const int chunkbase = (wave * 2 + cc) * 64;
      const int chunk = chunkbase + lane;
      const int row = chunk >> 2, col16 = chunk & 3;
      gload_lds16(A + (size_t)(bm + row) * K + k0 + col16 * 8,
                  &As[chunkbase * 8]);
      gload_lds16(Bt + (size_t)(bn + row) * K + k0 + col16 * 8,
                  &Bs[chunkbase * 8]);
    }
    __syncthreads();

    bf16x8 af[4], bfr[4];
    #pragma unroll
    for (int m = 0; m < 4; ++m)
      af[m] = *(const bf16x8*)&As[(wr * 64 + m * 16 + c) * 32 + g * 8];
    #pragma unroll
    for (int n = 0; n < 4; ++n)
      bfr[n] = *(const bf16x8*)&Bs[(wc * 64 + n * 16 + c) * 32 + g * 8];
    #pragma unroll
    for (int m = 0; m < 4; ++m)
      #pragma unroll
      for (int n = 0; n < 4; ++n)
        acc[m][n] = __builtin_amdgcn_mfma_f32_16x16x32_bf16(af[m], bfr[n], acc[m][n], 0, 0, 0);
  }

  #pragma unroll
  for (int n = 0; n < 4; ++n) {
    const int col = bn + wc * 64 + n * 16 + c;
    const float bs = bias[col];
    const float sc = (BF16OUT && col < scale_cols) ? scale : 1.f;
    #pragma unroll
    for (int m = 0; m < 4; ++m) {
      #pragma unroll
      for (int r = 0; r < 4; ++r) {
        const int row = bm + wr * 64 + m * 16 + g * 4 + r;
        const float v = acc[m][n][r] + bs;
        if (BF16OUT) Cb[(size_t)row * N + col] = f2bf(v * sc);
        else         Cf[(size_t)row * N + col] = v;
      }
    }
  }
}

// ---------------------------------------------------------------------------
// Causal flash attention, bf16 MFMA, fp32 accumulate.
// 4 waves/block, 16 q-rows/wave, q-tile pair {bx, 31-bx} per block.
// XCD-aware remap: all 16 blocks of one (b,h) land on one XCD (K/V L2-hot).
// Double-buffered K/V: global->reg issue overlaps previous tile's compute;
// reg->LDS write at iteration top; ONE barrier per tile.
// ---------------------------------------------------------------------------
__global__ __launch_bounds__(256) void attn_mfma(
    const short* __restrict__ qkv, short* __restrict__ y) {
  __shared__ short Ks[2][64][104];   // 26,624 B
  __shared__ short Vt[2][96][72];    // 27,648 B  (transposed V)
  __shared__ short Pl[4][16][72];    //  9,216 B

  // XCD remap: bid -> (pair p, sub bx); xcd = bid & 7 owns pairs {xcd+8k}
  const int bid = blockIdx.x;
  const int xcd = bid & 7, jj = bid >> 3;
  const int p = xcd + 8 * (jj >> 4);     // (b,h) pair 0..31
  const int bx = jj & 15;
  const int b = p >> 3, h = p & 7;

  const int tid  = threadIdx.x;
  const int wave = tid >> 6;
  const int lane = tid & 63;
  const int g = lane >> 4;
  const int c = lane & 15;

  int buf = 0;

  for (int phase = 0; phase < 2; ++phase) {
    const int qt = phase ? (31 - bx) : bx;
    const int q0 = qt * 64 + wave * 16;

    bf16x8 qf[3];
    {
      const size_t qb = ((size_t)(b * Tn + q0 + c)) * NQKV + h * HSn;
      #pragma unroll
      for (int kk = 0; kk < 3; ++kk)
        qf[kk] = *(const bf16x8*)(qkv + qb + kk * 32 + g * 8);
    }

    f32x4 yacc[6] = {};
    float mrow[4] = {-1e30f, -1e30f, -1e30f, -1e30f};
    float lrow[4] = {};

    // prologue: tile 0 into regs
    bf16x8 kreg[3], vreg[3];
    #pragma unroll
    for (int t = 0; t < 3; ++t) {
      const int i = tid + 256 * t;
      const int kr = i / 12, kc = i % 12;
      kreg[t] = *(const bf16x8*)(
          qkv + ((size_t)(b * Tn + kr)) * NQKV + Cn + h * HSn + kc * 8);
      const int vr = i & 63, vc = i >> 6;
      vreg[t] = *(const bf16x8*)(
          qkv + ((size_t)(b * Tn + vr)) * NQKV + 2 * Cn + h * HSn + vc * 8);
    }

    for (int kt = 0; kt <= qt; ++kt) {
      // ---- reg -> LDS[buf] (data loaded during previous tile's compute)
      #pragma unroll
      for (int t = 0; t < 3; ++t) {
        const int i = tid + 256 * t;
        const int kr = i / 12, kc = i % 12;
        *(bf16x8*)&Ks[buf][kr][kc * 8] = kreg[t];
        const int vr = i & 63, vc = i >> 6;   // vc is wave-uniform -> writes
        #pragma unroll                         // hit one row, consecutive cols
        for (int u = 0; u < 8; ++u) Vt[buf][vc * 8 + u][vr] = vreg[t][u];
      }
      __syncthreads();

      // ---- issue next tile's global loads (overlap with compute below)
      if (kt < qt) {
        const int k0n = (kt + 1) * 64;
        #pragma unroll
        for (int t = 0; t < 3; ++t) {
          const int i = tid + 256 * t;
          const int kr = i / 12, kc = i % 12;
          kreg[t] = *(const bf16x8*)(
              qkv + ((size_t)(b * Tn + k0n + kr)) * NQKV + Cn + h * HSn + kc * 8);
          const int vr = i & 63, vc = i >> 6;
          vreg[t] = *(const bf16x8*)(
              qkv + ((size_t)(b * Tn + k0n + vr)) * NQKV + 2 * Cn + h * HSn + vc * 8);
        }
      }

      const int k0 = kt * 64;

      // ---- S = Q K^T (scale folded into Q)
      f32x4 s[4] = {};
      __builtin_amdgcn_s_setprio(1);
      #pragma unroll
      for (int kk = 0; kk < 3; ++kk) {
        #pragma unroll
        for (int t = 0; t < 4; ++t) {
          bf16x8 kf = *(const bf16x8*)&Ks[buf][16 * t + c][32 * kk + g * 8];
          s[t] = __builtin_amdgcn_mfma_f32_16x16x32_bf16(qf[kk], kf, s[t], 0, 0, 0);
        }
      }
      __builtin_amdgcn_s_setprio(0);
      if (kt == qt) {
        #pragma unroll
        for (int t = 0; t < 4; ++t)
          #pragma unroll
          for (int r = 0; r < 4; ++r)
            if (k0 + 16 * t + c > q0 + 4 * g + r) s[t][r] = -1e30f;
      }

      // ---- online softmax
      #pragma unroll
      for (int r = 0; r < 4; ++r) {
        float mx = fmaxf(fmaxf(s[0][r], s[1][r]), fmaxf(s[2][r], s[3][r]));
        mx = fmaxf(mx, __shfl_xor(mx, 1));
        mx = fmaxf(mx, __shfl_xor(mx, 2));
        mx = fmaxf(mx, __shfl_xor(mx, 4));
        mx = fmaxf(mx, __shfl_xor(mx, 8));
        const float mnew = fmaxf(mrow[r], mx);
        const float corr = __expf(mrow[r] - mnew);
        mrow[r] = mnew;
        lrow[r] *= corr;
        #pragma unroll
        for (int dt = 0; dt < 6; ++dt) yacc[dt][r] *= corr;
        float ls = 0.f;
        #pragma unroll
        for (int t = 0; t < 4; ++t) {
          const float pv = __expf(s[t][r] - mnew);
          ls += pv;
          Pl[wave][4 * g + r][16 * t + c] = f2bf(pv);
        }
        lrow[r] += ls;
      }

      // ---- Y += P V
      __builtin_amdgcn_s_setprio(1);
      #pragma unroll
      for (int ks = 0; ks < 2; ++ks) {
        bf16x8 pf = *(const bf16x8*)&Pl[wave][c][ks * 32 + g * 8];
        #pragma unroll
        for (int dt = 0; dt < 6; ++dt) {
          bf16x8 vf = *(const bf16x8*)&Vt[buf][16 * dt + c][ks * 32 + g * 8];
          yacc[dt] = __builtin_amdgcn_mfma_f32_16x16x32_bf16(pf, vf, yacc[dt], 0, 0, 0);
        }
      }
      __builtin_amdgcn_s_setprio(0);

      buf ^= 1;
    }

    // ---- epilogue
    #pragma unroll
    for (int r = 0; r < 4; ++r) {
      float v = lrow[r];
      v += __shfl_xor(v, 1);
      v += __shfl_xor(v, 2);
      v += __shfl_xor(v, 4);
      v += __shfl_xor(v, 8);
      lrow[r] = 1.f / (v + 1e-6f);
    }
    #pragma unroll
    for (int dt = 0; dt < 6; ++dt)
      #pragma unroll
      for (int r = 0; r < 4; ++r)
        y[((size_t)(b * Tn + q0 + 4 * g + r)) * Cn + h * HSn + 16 * dt + c] =
            f2bf(yacc[dt][r] * lrow[r]);
  }
}

// ---------------------------------------------------------------------------
extern "C" void kernel_launch(void* const* d_in, const int* in_sizes, int n_in,
                              void* d_out, int out_size, void* d_ws, size_t ws_size,
                              hipStream_t stream) {
  const float* x      = (const float*)d_in[0];
  const float* w_attn = (const float*)d_in[1];
  const float* b_attn = (const float*)d_in[2];
  const float* w_proj = (const float*)d_in[3];
  const float* b_proj = (const float*)d_in[4];
  float* out = (float*)d_out;

  size_t off = 0;
  short* qkv = (short*)((char*)d_ws + off); off += (size_t)MR * NQKV * 2;
  short* xb  = (short*)((char*)d_ws + off); off += (size_t)MR * Cn * 2;
  short* yb  = (short*)((char*)d_ws + off); off += (size_t)MR * Cn * 2;
  short* wat = (short*)((char*)d_ws + off); off += (size_t)Cn * NQKV * 2;
  short* wpt = (short*)((char*)d_ws + off); off += (size_t)Cn * Cn * 2;
  if (ws_size < off) return;

  const float scale = 0.102062072615966f;  // 1/sqrt(96)

  // 0) precision prep
  cvt_bf16<<<(MR * Cn) / (256 * 8), 256, 0, stream>>>(x, xb);
  transpose_bf16<<<dim3(NQKV / 32, Cn / 32), 256, 0, stream>>>(w_attn, wat, Cn, NQKV);
  transpose_bf16<<<dim3(Cn / 32, Cn / 32), 256, 0, stream>>>(w_proj, wpt, Cn, Cn);

  // 1) qkv = x @ w_attn + b_attn   (bf16 out, q columns pre-scaled)
  gemm_mfma<true><<<(NQKV / 128) * (MR / 128), 256, 0, stream>>>(
      xb, wat, b_attn, nullptr, qkv, MR, NQKV, Cn, NQKV / 128, Cn, scale);

  // 2) causal MFMA attention -> y bf16 [B,T,C]
  attn_mfma<<<512, 256, 0, stream>>>(qkv, yb);

  // 3) out = y @ w_proj + b_proj   (fp32 out)
  gemm_mfma<false><<<(Cn / 128) * (MR / 128), 256, 0, stream>>>(
      yb, wpt, b_proj, out, nullptr, MR, Cn, Cn, Cn / 128, 0, 1.f);
}